// Round 3
// baseline (211.785 us; speedup 1.0000x reference)
//
#include <hip/hip_runtime.h>
#include <hip/hip_bf16.h>

typedef __attribute__((ext_vector_type(8))) short short8;
typedef __attribute__((ext_vector_type(4))) float f32x4;

#define MFMA16(a,b,c) __builtin_amdgcn_mfma_f32_16x16x32_bf16((a),(b),(c),0,0,0)

static __device__ __forceinline__ unsigned short f2b(float f){
  __hip_bfloat16 h = __float2bfloat16(f);
  return __builtin_bit_cast(unsigned short, h);
}

static __device__ __forceinline__ void gld_lds16(const void* g, void* l){
  __builtin_amdgcn_global_load_lds((const __attribute__((address_space(1))) unsigned int*)g,
                                   (__attribute__((address_space(3))) unsigned int*)l, 16, 0, 0);
}

// ---------------- elementwise f32 -> bf16 ----------------
__global__ __launch_bounds__(256) void k_convert_x(const float* __restrict__ x,
                                                   unsigned short* __restrict__ xb, int n){
  int i = (blockIdx.x*256 + threadIdx.x)*8;
  if (i >= n) return;
  float4 a = *(const float4*)(x+i);
  float4 b = *(const float4*)(x+i+4);
  short8 v;
  v[0]=f2b(a.x); v[1]=f2b(a.y); v[2]=f2b(a.z); v[3]=f2b(a.w);
  v[4]=f2b(b.x); v[5]=f2b(b.y); v[6]=f2b(b.z); v[7]=f2b(b.w);
  *(short8*)(xb+i) = v;
}

// ---------------- transpose + convert: in f32 [R][C] -> out bf16 [C][R] ----------------
__global__ void k_transpose_convert(const float* __restrict__ in,
                                    unsigned short* __restrict__ out, int R, int C){
  __shared__ float tile[32][33];
  int c0 = blockIdx.x*32, r0 = blockIdx.y*32;
  int tx = threadIdx.x, ty = threadIdx.y;
  #pragma unroll
  for (int i=0;i<4;i++) tile[ty*4+i][tx] = in[(size_t)(r0+ty*4+i)*C + c0+tx];
  __syncthreads();
  #pragma unroll
  for (int i=0;i<4;i++) out[(size_t)(c0+ty*4+i)*R + r0+tx] = f2b(tile[tx][ty*4+i]);
}

// ---------------- 256x256 8-phase bf16 GEMM: C[M][N] = A[M][K] * BT[N][K]^T ----------------
// 8 waves (2Mx4N), BK=64, 2-dbuf x 2-half LDS (128KiB), 4 phases/K-tile,
// counted vmcnt(4) once per tile BEFORE the final barrier (race-free ledger),
// XOR-8 chunk swizzle both-sides, setprio around MFMA clusters, XCD swizzle.
__global__ __launch_bounds__(512,2) void k_gemm8(const unsigned short* __restrict__ A,
    const unsigned short* __restrict__ BT, float* __restrict__ C,
    int M, int N, int K, int nbx){
  __shared__ unsigned short Abuf[2][2][128*64];
  __shared__ unsigned short Bbuf[2][2][128*64];
  const int NT = K >> 6;
  int cpx = gridDim.x >> 3;
  int bid = blockIdx.x;
  int swz = (bid & 7)*cpx + (bid >> 3);
  int bm = (swz / nbx)*256, bn = (swz % nbx)*256;
  int tid = threadIdx.x;
  int wave = tid >> 6, lane = tid & 63;
  int wr = wave >> 2;           // A half (M): 0..1
  int wcq = wave & 3;           // N quarter: 0..3
  int wcH = wcq >> 1;           // B half
  int brow = (wcq & 1)*64;      // row base inside B half
  int r = lane & 15, g = lane >> 4;

  f32x4 acc[8][4];
  #pragma unroll
  for (int i=0;i<8;i++)
    #pragma unroll
    for (int j=0;j<4;j++){ acc[i][j][0]=0.f; acc[i][j][1]=0.f; acc[i][j][2]=0.f; acc[i][j][3]=0.f; }

  // stage one half-tile (128 rows x 64 bf16 = 16KB): 2 x 16B per thread,
  // linear LDS dest + inverse-swizzled global source (chunk ^= row&7)
  #define STG_A(H, t) do{ if ((t) < NT){ unsigned short* dst = &Abuf[(t)&1][H][0];      \
      _Pragma("unroll") for (int i_=0;i_<2;++i_){ int c_ = tid + i_*512;                \
        int row_ = c_>>3, kc_ = c_&7;                                                   \
        gld_lds16(&A[(size_t)(bm + (H)*128 + row_)*K + (size_t)(t)*64 + ((kc_^(row_&7))*8)], \
                  &dst[c_*8]); } } }while(0)
  #define STG_B(H, t) do{ if ((t) < NT){ unsigned short* dst = &Bbuf[(t)&1][H][0];      \
      _Pragma("unroll") for (int i_=0;i_<2;++i_){ int c_ = tid + i_*512;                \
        int row_ = c_>>3, kc_ = c_&7;                                                   \
        gld_lds16(&BT[(size_t)(bn + (H)*128 + row_)*K + (size_t)(t)*64 + ((kc_^(row_&7))*8)], \
                  &dst[c_*8]); } } }while(0)

  #define LDA8(dst, frb) _Pragma("unroll") for (int fr_=0;fr_<4;++fr_)                  \
      _Pragma("unroll") for (int kk_=0;kk_<2;++kk_){ int row_ = ((frb)+fr_)*16 + r;     \
        dst[fr_][kk_] = *(const short8*)&Ab[row_*64 + (((kk_*4+g)^(row_&7))*8)]; }
  #define LDB4(dst, fcb) _Pragma("unroll") for (int fc_=0;fc_<2;++fc_)                  \
      _Pragma("unroll") for (int kk_=0;kk_<2;++kk_){ int row_ = brow + ((fcb)+fc_)*16 + r; \
        dst[fc_][kk_] = *(const short8*)&Bb[row_*64 + (((kk_*4+g)^(row_&7))*8)]; }

  #define MMA8(ar, ac, afv, bfv) _Pragma("unroll") for (int kk_=0;kk_<2;++kk_)          \
      _Pragma("unroll") for (int fr_=0;fr_<4;++fr_)                                     \
      _Pragma("unroll") for (int fc_=0;fc_<2;++fc_)                                     \
        acc[(ar)+fr_][(ac)+fc_] = MFMA16(afv[fr_][kk_], bfv[fc_][kk_], acc[(ar)+fr_][(ac)+fc_]);

  #define WAITL() do{ asm volatile("s_waitcnt lgkmcnt(0)" ::: "memory");                \
                      __builtin_amdgcn_sched_barrier(0); }while(0)

  // prologue: B0(0) A0(0) B1(0) A1(0) B0(1) A0(1); drain tile 0 (leave newest 4 loads)
  STG_B(0,0); STG_A(0,0); STG_B(1,0); STG_A(1,0); STG_B(0,1); STG_A(0,1);
  asm volatile("s_waitcnt vmcnt(4)" ::: "memory");
  __builtin_amdgcn_sched_barrier(0);
  __builtin_amdgcn_s_barrier();

  for (int t=0; t<NT; ++t){
    const unsigned short* Ab = &Abuf[t&1][wr][0];
    const unsigned short* Bb = &Bbuf[t&1][wcH][0];
    short8 af[4][2], bf0[2][2], bf1[2][2];
    // P0: q00  (reads A rows0-3 + B cols0-1; stage B1(t+1))
    LDA8(af, 0); LDB4(bf0, 0);
    STG_B(1, t+1);
    __builtin_amdgcn_s_barrier();
    WAITL();
    __builtin_amdgcn_s_setprio(1); MMA8(0,0,af,bf0); __builtin_amdgcn_s_setprio(0);
    __builtin_amdgcn_sched_barrier(0);
    __builtin_amdgcn_s_barrier();
    // P1: q01  (reads B cols2-3; stage A1(t+1))
    LDB4(bf1, 2);
    STG_A(1, t+1);
    __builtin_amdgcn_s_barrier();
    WAITL();
    __builtin_amdgcn_s_setprio(1); MMA8(0,2,af,bf1); __builtin_amdgcn_s_setprio(0);
    __builtin_amdgcn_sched_barrier(0);
    __builtin_amdgcn_s_barrier();
    // P2: q10  (reads A rows4-7; stage B0(t+2))
    LDA8(af, 4);
    STG_B(0, t+2);
    __builtin_amdgcn_s_barrier();
    WAITL();
    __builtin_amdgcn_s_setprio(1); MMA8(4,0,af,bf0); __builtin_amdgcn_s_setprio(0);
    __builtin_amdgcn_sched_barrier(0);
    __builtin_amdgcn_s_barrier();
    // P3: q11  (no reads; stage A0(t+2); counted vmcnt BEFORE final barrier)
    STG_A(0, t+2);
    __builtin_amdgcn_s_barrier();
    __builtin_amdgcn_s_setprio(1); MMA8(4,2,af,bf1); __builtin_amdgcn_s_setprio(0);
    __builtin_amdgcn_sched_barrier(0);
    asm volatile("s_waitcnt vmcnt(4)" ::: "memory");
    __builtin_amdgcn_sched_barrier(0);
    __builtin_amdgcn_s_barrier();
  }

  #pragma unroll
  for (int i=0;i<8;i++)
    #pragma unroll
    for (int j=0;j<4;j++)
      #pragma unroll
      for (int rr=0;rr<4;rr++)
        C[(size_t)(bm + wr*128 + i*16 + 4*g + rr)*N + bn + wcH*128 + brow + j*16 + r] = acc[i][j][rr];

  #undef STG_A
  #undef STG_B
  #undef LDA8
  #undef LDB4
  #undef MMA8
  #undef WAITL
}

// ---------------- RoPE + head split; Q scaled by log2(e)/sqrt(128) ----------------
__global__ __launch_bounds__(256) void k_rope_split(const float* __restrict__ qkv,
    const float* __restrict__ fc, unsigned short* __restrict__ qb,
    unsigned short* __restrict__ kb, unsigned short* __restrict__ vb){
  int row = blockIdx.x;              // b*2048 + t
  int t = row & 2047, b = row >> 11;
  int tid = threadIdx.x;
  const float* qr = qkv + (size_t)row*3072;
  const float QS = 0.12751743f;      // log2(e)/sqrt(128)
  #pragma unroll
  for (int ii=0; ii<4; ii++){        // 1024 q pairs
    int p = tid + 256*ii;
    int h = p>>6, f = p&63;
    float x0 = qr[h*128 + 2*f], x1 = qr[h*128 + 2*f + 1];
    float cs = fc[t*128 + 2*f], sn = fc[t*128 + 2*f + 1];
    float o0 = (x0*cs - x1*sn)*QS, o1 = (x0*sn + x1*cs)*QS;
    size_t o = ((size_t)(b*16 + h)*2048 + t)*128 + 2*f;
    qb[o] = f2b(o0); qb[o+1] = f2b(o1);
  }
  {                                   // 256 k pairs
    int p = tid; int kh = p>>6, f = p&63;
    float x0 = qr[2048 + kh*128 + 2*f], x1 = qr[2048 + kh*128 + 2*f + 1];
    float cs = fc[t*128 + 2*f], sn = fc[t*128 + 2*f + 1];
    float o0 = x0*cs - x1*sn, o1 = x0*sn + x1*cs;
    size_t o = ((size_t)(b*4 + kh)*2048 + t)*128 + 2*f;
    kb[o] = f2b(o0); kb[o+1] = f2b(o1);
  }
  #pragma unroll
  for (int ii=0; ii<2; ii++){         // 512 v elems
    int e = tid + 256*ii;
    int kh = e>>7, d = e&127;
    size_t o = ((size_t)(b*4 + kh)*2048 + t)*128 + d;
    vb[o] = f2b(qr[2560 + e]);
  }
}

// ---------------- V transpose: [bk][2048][128] -> [bk][128][2048] ----------------
__global__ void k_transpose_v(const unsigned short* __restrict__ v,
                              unsigned short* __restrict__ vt){
  __shared__ unsigned short tile[32][33];
  int bk = blockIdx.z;
  int d0 = blockIdx.x*32, t0 = blockIdx.y*32;
  int tx = threadIdx.x, ty = threadIdx.y;
  const unsigned short* vp = v + (size_t)bk*2048*128;
  unsigned short* vtp = vt + (size_t)bk*128*2048;
  #pragma unroll
  for (int i=0;i<4;i++) tile[ty*4+i][tx] = vp[(t0+ty*4+i)*128 + d0+tx];
  __syncthreads();
  #pragma unroll
  for (int i=0;i<4;i++) vtp[(d0+ty*4+i)*2048 + t0+tx] = tile[tx][ty*4+i];
}

// ---------------- sliding-window flash attention, LDS-staged K/V ----------------
__global__ __launch_bounds__(256,2) void k_attn(const unsigned short* __restrict__ q,
    const unsigned short* __restrict__ k, const unsigned short* __restrict__ vt,
    unsigned short* __restrict__ y){
  int qb0 = blockIdx.x*64;
  int h = blockIdx.y, b = blockIdx.z;
  int kvh = h>>2;
  int tid = threadIdx.x, wave = tid>>6, lane = tid&63;
  int w0 = qb0 + wave*16;
  int r = lane&15, g = lane>>4;
  const unsigned short* qh = q + ((size_t)(b*16+h)*2048)*128;
  const unsigned short* kh = k + ((size_t)(b*4+kvh)*2048)*128;
  const unsigned short* vh = vt + ((size_t)(b*4+kvh)*128)*2048;

  __shared__ unsigned short Ks[2][64*128];   // [key][d], swizzled
  __shared__ unsigned short Vs[2][128*64];   // [d][key], swizzled
  __shared__ unsigned short plds[4][16][72];

  short8 qf[4];
  #pragma unroll
  for (int c=0;c<4;c++) qf[c] = *(const short8*)&qh[(w0+r)*128 + c*32 + g*8];

  f32x4 acc[8];
  #pragma unroll
  for (int d=0; d<8; d++){ acc[d][0]=0.f; acc[d][1]=0.f; acc[d][2]=0.f; acc[d][3]=0.f; }
  float m[4]  = {-1e30f,-1e30f,-1e30f,-1e30f};
  float ls[4] = {0.f,0.f,0.f,0.f};

  int lo = qb0 - 511; if (lo < 0) lo = 0;
  int t0 = lo & ~63;
  int nt = ((qb0 + 63) - t0)/64 + 1;
  int sw = (r&7)<<4;                 // per-lane read swizzle (row&7 == r&7)

  #define STAGE(bb, kt)                                                          \
    { _Pragma("unroll")                                                          \
      for (int p=0;p<4;p++){                                                     \
        int c = p*256 + tid;                                                     \
        int row = c>>4, col = (c&15)*16;                                         \
        gld_lds16((const char*)kh + (size_t)((kt)+row)*256 + (col ^ ((row&7)<<4)),\
                  (char*)&Ks[bb][0] + c*16);                                     \
      }                                                                          \
      _Pragma("unroll")                                                          \
      for (int p=0;p<4;p++){                                                     \
        int c = p*256 + tid;                                                     \
        int row = c>>3, col = (c&7)*16;                                          \
        gld_lds16((const char*)vh + (size_t)row*4096 + (size_t)(kt)*2 + (col ^ ((row&7)<<4)),\
                  (char*)&Vs[bb][0] + c*16);                                     \
      }                                                                          \
    }

  STAGE(0, t0);
  __syncthreads();
  int cur = 0;

  for (int it=0; it<nt; it++){
    int kt = t0 + it*64;
    if (it+1 < nt) STAGE(cur^1, t0 + (it+1)*64);

    bool use = (kt <= w0+15) && (kt+63 >= w0-511);
    if (use){
      f32x4 S[4];
      #pragma unroll
      for (int s=0;s<4;s++){
        f32x4 a; a[0]=0.f; a[1]=0.f; a[2]=0.f; a[3]=0.f;
        const char* kr = (const char*)&Ks[cur][0] + (s*16+r)*256;
        #pragma unroll
        for (int c=0;c<4;c++){
          short8 kf = *(const short8*)(kr + ((c*64 + g*16) ^ sw));
          a = MFMA16(qf[c], kf, a);
        }
        S[s] = a;
      }
      #pragma unroll
      for (int rr=0;rr<4;rr++){
        int i = w0 + 4*g + rr;
        float mx = -3e38f;
        #pragma unroll
        for (int s=0;s<4;s++){
          int j = kt + s*16 + r;
          bool valid = (j <= i) && (i - j < 512);
          float sv = valid ? S[s][rr] : -3e38f;
          S[s][rr] = sv;
          mx = fmaxf(mx, sv);
        }
        mx = fmaxf(mx, __shfl_xor(mx, 1));
        mx = fmaxf(mx, __shfl_xor(mx, 2));
        mx = fmaxf(mx, __shfl_xor(mx, 4));
        mx = fmaxf(mx, __shfl_xor(mx, 8));
        float mn = fmaxf(m[rr], mx);
        float al = exp2f(m[rr] - mn);
        m[rr] = mn;
        float ps = 0.f;
        #pragma unroll
        for (int s=0;s<4;s++){
          float p = exp2f(S[s][rr] - mn);
          S[s][rr] = p;
          ps += p;
        }
        ls[rr] = ls[rr]*al + ps;
        #pragma unroll
        for (int d=0;d<8;d++) acc[d][rr] *= al;
      }
      #pragma unroll
      for (int rr=0;rr<4;rr++)
        #pragma unroll
        for (int s=0;s<4;s++)
          plds[wave][4*g+rr][s*16+r] = f2b(S[s][rr]);
      short8 pf0 = *(const short8*)&plds[wave][r][g*8];
      short8 pf1 = *(const short8*)&plds[wave][r][32 + g*8];
      #pragma unroll
      for (int d=0;d<8;d++){
        const char* vr = (const char*)&Vs[cur][0] + (d*16+r)*128;
        short8 vf0 = *(const short8*)(vr + ((g*16) ^ sw));
        short8 vf1 = *(const short8*)(vr + ((64 + g*16) ^ sw));
        acc[d] = MFMA16(pf0, vf0, acc[d]);
        acc[d] = MFMA16(pf1, vf1, acc[d]);
      }
    }
    __syncthreads();
    cur ^= 1;
  }

  #pragma unroll
  for (int rr=0;rr<4;rr++){
    float s = ls[rr];
    s += __shfl_xor(s, 1);
    s += __shfl_xor(s, 2);
    s += __shfl_xor(s, 4);
    s += __shfl_xor(s, 8);
    float inv = 1.f/s;
    int i = w0 + 4*g + rr;
    #pragma unroll
    for (int d=0;d<8;d++)
      y[((size_t)(b*2048)+i)*2048 + h*128 + d*16 + r] = f2b(acc[d][rr]*inv);
  }
}

extern "C" void kernel_launch(void* const* d_in, const int* in_sizes, int n_in,
                              void* d_out, int out_size, void* d_ws, size_t ws_size,
                              hipStream_t stream) {
  const float* x      = (const float*)d_in[0];
  const float* w_attn = (const float*)d_in[1];
  const float* w_proj = (const float*)d_in[2];
  const float* fc     = (const float*)d_in[3];
  float* out = (float*)d_out;
  char* ws = (char*)d_ws;
  unsigned short* xb  = (unsigned short*)(ws);             // 16,777,216  x bf16
  unsigned short* wt  = (unsigned short*)(ws + 16777216);  // 12,582,912  w^T bf16 (reused for w_proj^T)
  float*          qkv = (float*)(ws + 29360128);           // 50,331,648  qkv f32
  unsigned short* yb  = (unsigned short*)(ws + 29360128);  // reuse qkv slot after rope
  unsigned short* qb  = (unsigned short*)(ws + 79691776);  // 16,777,216
  unsigned short* kb  = (unsigned short*)(ws + 96468992);  //  4,194,304
  unsigned short* vb  = (unsigned short*)(ws + 100663296); //  4,194,304
  unsigned short* vtb = (unsigned short*)(ws + 104857600); //  4,194,304

  k_convert_x<<<4096, 256, 0, stream>>>(x, xb, 8388608);
  k_transpose_convert<<<dim3(96,64), dim3(32,8), 0, stream>>>(w_attn, wt, 2048, 3072);
  k_gemm8<<<dim3(192), 512, 0, stream>>>(xb, wt, qkv, 4096, 3072, 2048, 12);
  k_rope_split<<<4096, 256, 0, stream>>>(qkv, fc, qb, kb, vb);
  k_transpose_v<<<dim3(4,64,8), dim3(32,8), 0, stream>>>(vb, vtb);
  k_transpose_convert<<<dim3(64,64), dim3(32,8), 0, stream>>>(w_proj, wt, 2048, 2048);
  k_attn<<<dim3(32,16,2), 256, 0, stream>>>(qb, kb, vtb, yb);
  k_gemm8<<<dim3(128), 512, 0, stream>>>(yb, wt, out, 4096, 2048, 2048, 8);
}

// Round 4
// 211.366 us; speedup vs baseline: 1.0020x; 1.0020x over previous
//
#include <hip/hip_runtime.h>
#include <hip/hip_bf16.h>

typedef __attribute__((ext_vector_type(8))) short short8;
typedef __attribute__((ext_vector_type(4))) float f32x4;

#define MFMA16(a,b,c) __builtin_amdgcn_mfma_f32_16x16x32_bf16((a),(b),(c),0,0,0)

static __device__ __forceinline__ unsigned short f2b(float f){
  __hip_bfloat16 h = __float2bfloat16(f);
  return __builtin_bit_cast(unsigned short, h);
}
static __device__ __forceinline__ float b2f(unsigned short u){
  unsigned int v = ((unsigned int)u)<<16;
  return __builtin_bit_cast(float, v);
}

static __device__ __forceinline__ void gld_lds16(const void* g, void* l){
  __builtin_amdgcn_global_load_lds((const __attribute__((address_space(1))) unsigned int*)g,
                                   (__attribute__((address_space(3))) unsigned int*)l, 16, 0, 0);
}

// ---------------- elementwise f32 -> bf16 ----------------
__global__ __launch_bounds__(256) void k_convert_x(const float* __restrict__ x,
                                                   unsigned short* __restrict__ xb, int n){
  int i = (blockIdx.x*256 + threadIdx.x)*8;
  if (i >= n) return;
  float4 a = *(const float4*)(x+i);
  float4 b = *(const float4*)(x+i+4);
  short8 v;
  v[0]=f2b(a.x); v[1]=f2b(a.y); v[2]=f2b(a.z); v[3]=f2b(a.w);
  v[4]=f2b(b.x); v[5]=f2b(b.y); v[6]=f2b(b.z); v[7]=f2b(b.w);
  *(short8*)(xb+i) = v;
}

// ---------------- transpose + convert: in f32 [R][C] -> out bf16 [C][R] ----------------
__global__ void k_transpose_convert(const float* __restrict__ in,
                                    unsigned short* __restrict__ out, int R, int C){
  __shared__ float tile[32][33];
  int c0 = blockIdx.x*32, r0 = blockIdx.y*32;
  int tx = threadIdx.x, ty = threadIdx.y;
  #pragma unroll
  for (int i=0;i<4;i++) tile[ty*4+i][tx] = in[(size_t)(r0+ty*4+i)*C + c0+tx];
  __syncthreads();
  #pragma unroll
  for (int i=0;i<4;i++) out[(size_t)(c0+ty*4+i)*R + r0+tx] = f2b(tile[tx][ty*4+i]);
}

// ---------------- 256x256 8-phase bf16 GEMM ----------------
// 8 waves (2Mx4N), BK=64, 2-dbuf LDS (128KiB), 2 K-tiles/iter (static parity),
// all four (t+2) half-tiles staged late in tile t (B in P2, A in P3) ->
// single counted vmcnt(8)/K-tile keeps 4 half-tiles in flight.
// XOR-8 chunk swizzle both-sides; setprio around MFMA; XCD swizzle.
template<int OB>   // OB=1: write bf16 C, OB=0: write f32 C
__global__ __launch_bounds__(512,2) void k_gemm8(const unsigned short* __restrict__ A,
    const unsigned short* __restrict__ BT, void* __restrict__ Cv,
    int M, int N, int K, int nbx){
  __shared__ unsigned short Abuf[2][2][128*64];
  __shared__ unsigned short Bbuf[2][2][128*64];
  const int NT = K >> 6;               // even (K=2048 -> 32)
  int cpx = gridDim.x >> 3;
  int bid = blockIdx.x;
  int swz = (bid & 7)*cpx + (bid >> 3);
  int bm = (swz / nbx)*256, bn = (swz % nbx)*256;
  int tid = threadIdx.x;
  int wave = tid >> 6, lane = tid & 63;
  int wr = wave >> 2;           // A half (M)
  int wcq = wave & 3;           // N quarter
  int wcH = wcq >> 1;           // B half
  int brow = (wcq & 1)*64;
  int r = lane & 15, g = lane >> 4;

  f32x4 acc[8][4];
  #pragma unroll
  for (int i=0;i<8;i++)
    #pragma unroll
    for (int j=0;j<4;j++){ acc[i][j][0]=0.f; acc[i][j][1]=0.f; acc[i][j][2]=0.f; acc[i][j][3]=0.f; }

  #define STG_A(p, H, t) do{ if ((t) < NT){ unsigned short* dst = &Abuf[p][H][0];       \
      _Pragma("unroll") for (int i_=0;i_<2;++i_){ int c_ = tid + i_*512;                \
        int row_ = c_>>3, kc_ = c_&7;                                                   \
        gld_lds16(&A[(size_t)(bm + (H)*128 + row_)*K + (size_t)(t)*64 + ((kc_^(row_&7))*8)], \
                  &dst[c_*8]); } } }while(0)
  #define STG_B(p, H, t) do{ if ((t) < NT){ unsigned short* dst = &Bbuf[p][H][0];       \
      _Pragma("unroll") for (int i_=0;i_<2;++i_){ int c_ = tid + i_*512;                \
        int row_ = c_>>3, kc_ = c_&7;                                                   \
        gld_lds16(&BT[(size_t)(bn + (H)*128 + row_)*K + (size_t)(t)*64 + ((kc_^(row_&7))*8)], \
                  &dst[c_*8]); } } }while(0)

  #define LDA8(dst, frb) _Pragma("unroll") for (int fr_=0;fr_<4;++fr_)                  \
      _Pragma("unroll") for (int kk_=0;kk_<2;++kk_){ int row_ = ((frb)+fr_)*16 + r;     \
        dst[fr_][kk_] = *(const short8*)&Ab[row_*64 + (((kk_*4+g)^(row_&7))*8)]; }
  #define LDB4(dst, fcb) _Pragma("unroll") for (int fc_=0;fc_<2;++fc_)                  \
      _Pragma("unroll") for (int kk_=0;kk_<2;++kk_){ int row_ = brow + ((fcb)+fc_)*16 + r; \
        dst[fc_][kk_] = *(const short8*)&Bb[row_*64 + (((kk_*4+g)^(row_&7))*8)]; }

  #define MMA8(ar, ac, afv, bfv) _Pragma("unroll") for (int kk_=0;kk_<2;++kk_)          \
      _Pragma("unroll") for (int fr_=0;fr_<4;++fr_)                                     \
      _Pragma("unroll") for (int fc_=0;fc_<2;++fc_)                                     \
        acc[(ar)+fr_][(ac)+fc_] = MFMA16(afv[fr_][kk_], bfv[fc_][kk_], acc[(ar)+fr_][(ac)+fc_]);

  #define WAITL() do{ asm volatile("s_waitcnt lgkmcnt(0)" ::: "memory");                \
                      __builtin_amdgcn_sched_barrier(0); }while(0)
  #define BAR() __builtin_amdgcn_s_barrier()
  #define PRIO1 __builtin_amdgcn_s_setprio(1)
  #define PRIO0 __builtin_amdgcn_s_setprio(0)

  // KTILE: 4 phases; (t+2) halves staged late (B in P2 after last B read,
  // A in P3 after last A read); one vmcnt(8) per tile before the final barrier.
  #define KTILE(p, t) do{                                                               \
    const unsigned short* Ab = &Abuf[p][wr][0];                                         \
    const unsigned short* Bb = &Bbuf[p][wcH][0];                                        \
    short8 af[4][2], bf0[2][2], bf1[2][2];                                              \
    LDA8(af, 0); LDB4(bf0, 0);                                                          \
    BAR(); WAITL();                                                                     \
    PRIO1; MMA8(0,0,af,bf0); PRIO0;                                                     \
    BAR();                                                                              \
    LDB4(bf1, 2);                                                                       \
    BAR(); WAITL();                                                                     \
    PRIO1; MMA8(0,2,af,bf1); PRIO0;                                                     \
    BAR();                                                                              \
    LDA8(af, 4);                                                                        \
    STG_B(p, 0, (t)+2); STG_B(p, 1, (t)+2);                                             \
    BAR(); WAITL();                                                                     \
    PRIO1; MMA8(4,0,af,bf0); PRIO0;                                                     \
    BAR();                                                                              \
    STG_A(p, 0, (t)+2); STG_A(p, 1, (t)+2);                                             \
    BAR();                                                                              \
    PRIO1; MMA8(4,2,af,bf1); PRIO0;                                                     \
    asm volatile("s_waitcnt vmcnt(8)" ::: "memory");                                    \
    __builtin_amdgcn_sched_barrier(0);                                                  \
    BAR();                                                                              \
  }while(0)

  // prologue: stage tiles 0 and 1 fully; drain tile 0, leave tile 1 in flight
  STG_B(0,0,0); STG_B(0,1,0); STG_A(0,0,0); STG_A(0,1,0);
  STG_B(1,0,1); STG_B(1,1,1); STG_A(1,0,1); STG_A(1,1,1);
  asm volatile("s_waitcnt vmcnt(8)" ::: "memory");
  __builtin_amdgcn_sched_barrier(0);
  BAR();

  for (int tt=0; tt<NT; tt+=2){
    KTILE(0, tt);
    KTILE(1, tt+1);
  }

  #pragma unroll
  for (int i=0;i<8;i++)
    #pragma unroll
    for (int j=0;j<4;j++)
      #pragma unroll
      for (int rr=0;rr<4;rr++){
        size_t idx = (size_t)(bm + wr*128 + i*16 + 4*g + rr)*N + bn + wcH*128 + brow + j*16 + r;
        if (OB) ((unsigned short*)Cv)[idx] = f2b(acc[i][j][rr]);
        else    ((float*)Cv)[idx] = acc[i][j][rr];
      }

  #undef STG_A
  #undef STG_B
  #undef LDA8
  #undef LDB4
  #undef MMA8
  #undef WAITL
  #undef BAR
  #undef PRIO1
  #undef PRIO0
  #undef KTILE
}

// ---------------- RoPE + head split (bf16 qkv in); Q scaled by log2(e)/sqrt(128) ----------------
__global__ __launch_bounds__(256) void k_rope_split(const unsigned short* __restrict__ qkv,
    const float* __restrict__ fc, unsigned short* __restrict__ qb,
    unsigned short* __restrict__ kb, unsigned short* __restrict__ vb){
  int row = blockIdx.x;              // b*2048 + t
  int t = row & 2047, b = row >> 11;
  int tid = threadIdx.x;
  const unsigned short* qr = qkv + (size_t)row*3072;
  const float QS = 0.12751743f;      // log2(e)/sqrt(128)
  #pragma unroll
  for (int ii=0; ii<4; ii++){        // 1024 q pairs
    int p = tid + 256*ii;
    int h = p>>6, f = p&63;
    unsigned int pr = *(const unsigned int*)&qr[h*128 + 2*f];
    float x0 = b2f((unsigned short)(pr & 0xffff)), x1 = b2f((unsigned short)(pr >> 16));
    float2 cssn = *(const float2*)&fc[t*128 + 2*f];
    float o0 = (x0*cssn.x - x1*cssn.y)*QS, o1 = (x0*cssn.y + x1*cssn.x)*QS;
    size_t o = ((size_t)(b*16 + h)*2048 + t)*128 + 2*f;
    qb[o] = f2b(o0); qb[o+1] = f2b(o1);
  }
  {                                   // 256 k pairs
    int p = tid; int kh = p>>6, f = p&63;
    unsigned int pr = *(const unsigned int*)&qr[2048 + kh*128 + 2*f];
    float x0 = b2f((unsigned short)(pr & 0xffff)), x1 = b2f((unsigned short)(pr >> 16));
    float2 cssn = *(const float2*)&fc[t*128 + 2*f];
    float o0 = x0*cssn.x - x1*cssn.y, o1 = x0*cssn.y + x1*cssn.x;
    size_t o = ((size_t)(b*4 + kh)*2048 + t)*128 + 2*f;
    kb[o] = f2b(o0); kb[o+1] = f2b(o1);
  }
  #pragma unroll
  for (int ii=0; ii<2; ii++){         // 512 v elems
    int e = tid + 256*ii;
    int kh = e>>7, d = e&127;
    size_t o = ((size_t)(b*4 + kh)*2048 + t)*128 + d;
    vb[o] = qr[2560 + e];
  }
}

// ---------------- V transpose: [bk][2048][128] -> [bk][128][2048] ----------------
__global__ void k_transpose_v(const unsigned short* __restrict__ v,
                              unsigned short* __restrict__ vt){
  __shared__ unsigned short tile[32][33];
  int bk = blockIdx.z;
  int d0 = blockIdx.x*32, t0 = blockIdx.y*32;
  int tx = threadIdx.x, ty = threadIdx.y;
  const unsigned short* vp = v + (size_t)bk*2048*128;
  unsigned short* vtp = vt + (size_t)bk*128*2048;
  #pragma unroll
  for (int i=0;i<4;i++) tile[ty*4+i][tx] = vp[(t0+ty*4+i)*128 + d0+tx];
  __syncthreads();
  #pragma unroll
  for (int i=0;i<4;i++) vtp[(d0+ty*4+i)*2048 + t0+tx] = tile[tx][ty*4+i];
}

// ---------------- sliding-window flash attention, LDS-staged K/V ----------------
__global__ __launch_bounds__(256,2) void k_attn(const unsigned short* __restrict__ q,
    const unsigned short* __restrict__ k, const unsigned short* __restrict__ vt,
    unsigned short* __restrict__ y){
  int qb0 = blockIdx.x*64;
  int h = blockIdx.y, b = blockIdx.z;
  int kvh = h>>2;
  int tid = threadIdx.x, wave = tid>>6, lane = tid&63;
  int w0 = qb0 + wave*16;
  int r = lane&15, g = lane>>4;
  const unsigned short* qh = q + ((size_t)(b*16+h)*2048)*128;
  const unsigned short* kh = k + ((size_t)(b*4+kvh)*2048)*128;
  const unsigned short* vh = vt + ((size_t)(b*4+kvh)*128)*2048;

  __shared__ unsigned short Ks[2][64*128];   // [key][d], swizzled
  __shared__ unsigned short Vs[2][128*64];   // [d][key], swizzled
  __shared__ unsigned short plds[4][16][72];

  short8 qf[4];
  #pragma unroll
  for (int c=0;c<4;c++) qf[c] = *(const short8*)&qh[(w0+r)*128 + c*32 + g*8];

  f32x4 acc[8];
  #pragma unroll
  for (int d=0; d<8; d++){ acc[d][0]=0.f; acc[d][1]=0.f; acc[d][2]=0.f; acc[d][3]=0.f; }
  float m[4]  = {-1e30f,-1e30f,-1e30f,-1e30f};
  float ls[4] = {0.f,0.f,0.f,0.f};

  int lo = qb0 - 511; if (lo < 0) lo = 0;
  int t0 = lo & ~63;
  int nt = ((qb0 + 63) - t0)/64 + 1;
  int sw = (r&7)<<4;                 // per-lane read swizzle (row&7 == r&7)

  #define STAGE(bb, kt)                                                          \
    { _Pragma("unroll")                                                          \
      for (int p=0;p<4;p++){                                                     \
        int c = p*256 + tid;                                                     \
        int row = c>>4, col = (c&15)*16;                                         \
        gld_lds16((const char*)kh + (size_t)((kt)+row)*256 + (col ^ ((row&7)<<4)),\
                  (char*)&Ks[bb][0] + c*16);                                     \
      }                                                                          \
      _Pragma("unroll")                                                          \
      for (int p=0;p<4;p++){                                                     \
        int c = p*256 + tid;                                                     \
        int row = c>>3, col = (c&7)*16;                                          \
        gld_lds16((const char*)vh + (size_t)row*4096 + (size_t)(kt)*2 + (col ^ ((row&7)<<4)),\
                  (char*)&Vs[bb][0] + c*16);                                     \
      }                                                                          \
    }

  STAGE(0, t0);
  __syncthreads();
  int cur = 0;

  for (int it=0; it<nt; it++){
    int kt = t0 + it*64;
    if (it+1 < nt) STAGE(cur^1, t0 + (it+1)*64);

    bool use = (kt <= w0+15) && (kt+63 >= w0-511);
    if (use){
      f32x4 S[4];
      #pragma unroll
      for (int s=0;s<4;s++){
        f32x4 a; a[0]=0.f; a[1]=0.f; a[2]=0.f; a[3]=0.f;
        const char* kr = (const char*)&Ks[cur][0] + (s*16+r)*256;
        #pragma unroll
        for (int c=0;c<4;c++){
          short8 kf = *(const short8*)(kr + ((c*64 + g*16) ^ sw));
          a = MFMA16(qf[c], kf, a);
        }
        S[s] = a;
      }
      #pragma unroll
      for (int rr=0;rr<4;rr++){
        int i = w0 + 4*g + rr;
        float mx = -3e38f;
        #pragma unroll
        for (int s=0;s<4;s++){
          int j = kt + s*16 + r;
          bool valid = (j <= i) && (i - j < 512);
          float sv = valid ? S[s][rr] : -3e38f;
          S[s][rr] = sv;
          mx = fmaxf(mx, sv);
        }
        mx = fmaxf(mx, __shfl_xor(mx, 1));
        mx = fmaxf(mx, __shfl_xor(mx, 2));
        mx = fmaxf(mx, __shfl_xor(mx, 4));
        mx = fmaxf(mx, __shfl_xor(mx, 8));
        float mn = fmaxf(m[rr], mx);
        float al = exp2f(m[rr] - mn);
        m[rr] = mn;
        float ps = 0.f;
        #pragma unroll
        for (int s=0;s<4;s++){
          float p = exp2f(S[s][rr] - mn);
          S[s][rr] = p;
          ps += p;
        }
        ls[rr] = ls[rr]*al + ps;
        #pragma unroll
        for (int d=0;d<8;d++) acc[d][rr] *= al;
      }
      #pragma unroll
      for (int rr=0;rr<4;rr++)
        #pragma unroll
        for (int s=0;s<4;s++)
          plds[wave][4*g+rr][s*16+r] = f2b(S[s][rr]);
      short8 pf0 = *(const short8*)&plds[wave][r][g*8];
      short8 pf1 = *(const short8*)&plds[wave][r][32 + g*8];
      #pragma unroll
      for (int d=0;d<8;d++){
        const char* vr = (const char*)&Vs[cur][0] + (d*16+r)*128;
        short8 vf0 = *(const short8*)(vr + ((g*16) ^ sw));
        short8 vf1 = *(const short8*)(vr + ((64 + g*16) ^ sw));
        acc[d] = MFMA16(pf0, vf0, acc[d]);
        acc[d] = MFMA16(pf1, vf1, acc[d]);
      }
    }
    __syncthreads();
    cur ^= 1;
  }

  #pragma unroll
  for (int rr=0;rr<4;rr++){
    float s = ls[rr];
    s += __shfl_xor(s, 1);
    s += __shfl_xor(s, 2);
    s += __shfl_xor(s, 4);
    s += __shfl_xor(s, 8);
    float inv = 1.f/s;
    int i = w0 + 4*g + rr;
    #pragma unroll
    for (int d=0;d<8;d++)
      y[((size_t)(b*2048)+i)*2048 + h*128 + d*16 + r] = f2b(acc[d][rr]*inv);
  }
}

extern "C" void kernel_launch(void* const* d_in, const int* in_sizes, int n_in,
                              void* d_out, int out_size, void* d_ws, size_t ws_size,
                              hipStream_t stream) {
  const float* x      = (const float*)d_in[0];
  const float* w_attn = (const float*)d_in[1];
  const float* w_proj = (const float*)d_in[2];
  const float* fc     = (const float*)d_in[3];
  float* out = (float*)d_out;
  char* ws = (char*)d_ws;
  unsigned short* xb   = (unsigned short*)(ws);             // 16,777,216  x bf16
  unsigned short* wt   = (unsigned short*)(ws + 16777216);  // 12,582,912  w^T bf16 (reused)
  unsigned short* qkvb = (unsigned short*)(ws + 29360128);  // 25,165,824  qkv bf16
  unsigned short* yb   = (unsigned short*)(ws + 29360128);  // reuse after rope
  unsigned short* qb   = (unsigned short*)(ws + 54525952);  // 16,777,216
  unsigned short* kb   = (unsigned short*)(ws + 71303168);  //  4,194,304
  unsigned short* vb   = (unsigned short*)(ws + 75497472);  //  4,194,304
  unsigned short* vtb  = (unsigned short*)(ws + 79691776);  //  4,194,304

  k_convert_x<<<4096, 256, 0, stream>>>(x, xb, 8388608);
  k_transpose_convert<<<dim3(96,64), dim3(32,8), 0, stream>>>(w_attn, wt, 2048, 3072);
  k_gemm8<1><<<dim3(192), 512, 0, stream>>>(xb, wt, qkvb, 4096, 3072, 2048, 12);
  k_rope_split<<<4096, 256, 0, stream>>>(qkvb, fc, qb, kb, vb);
  k_transpose_v<<<dim3(4,64,8), dim3(32,8), 0, stream>>>(vb, vtb);
  k_transpose_convert<<<dim3(64,64), dim3(32,8), 0, stream>>>(w_proj, wt, 2048, 2048);
  k_attn<<<dim3(32,16,2), 256, 0, stream>>>(qb, kb, vtb, yb);
  k_gemm8<0><<<dim3(128), 512, 0, stream>>>(yb, wt, out, 4096, 2048, 2048, 8);
}

// Round 5
// 191.050 us; speedup vs baseline: 1.1085x; 1.1063x over previous
//
#include <hip/hip_runtime.h>
#include <hip/hip_bf16.h>

typedef __attribute__((ext_vector_type(8))) short short8;
typedef __attribute__((ext_vector_type(4))) float f32x4;

#define MFMA16(a,b,c) __builtin_amdgcn_mfma_f32_16x16x32_bf16((a),(b),(c),0,0,0)

static __device__ __forceinline__ unsigned short f2b(float f){
  __hip_bfloat16 h = __float2bfloat16(f);
  return __builtin_bit_cast(unsigned short, h);
}
static __device__ __forceinline__ float b2f(unsigned short u){
  unsigned int v = ((unsigned int)u)<<16;
  return __builtin_bit_cast(float, v);
}

static __device__ __forceinline__ void gld_lds16(const void* g, void* l){
  __builtin_amdgcn_global_load_lds((const __attribute__((address_space(1))) unsigned int*)g,
                                   (__attribute__((address_space(3))) unsigned int*)l, 16, 0, 0);
}

// ---------------- elementwise f32 -> bf16 ----------------
__global__ __launch_bounds__(256) void k_convert_x(const float* __restrict__ x,
                                                   unsigned short* __restrict__ xb, int n){
  int i = (blockIdx.x*256 + threadIdx.x)*8;
  if (i >= n) return;
  float4 a = *(const float4*)(x+i);
  float4 b = *(const float4*)(x+i+4);
  short8 v;
  v[0]=f2b(a.x); v[1]=f2b(a.y); v[2]=f2b(a.z); v[3]=f2b(a.w);
  v[4]=f2b(b.x); v[5]=f2b(b.y); v[6]=f2b(b.z); v[7]=f2b(b.w);
  *(short8*)(xb+i) = v;
}

// ---------------- transpose + convert: in f32 [R][C] -> out bf16 [C][R] ----------------
__global__ void k_transpose_convert(const float* __restrict__ in,
                                    unsigned short* __restrict__ out, int R, int C){
  __shared__ float tile[32][33];
  int c0 = blockIdx.x*32, r0 = blockIdx.y*32;
  int tx = threadIdx.x, ty = threadIdx.y;
  #pragma unroll
  for (int i=0;i<4;i++) tile[ty*4+i][tx] = in[(size_t)(r0+ty*4+i)*C + c0+tx];
  __syncthreads();
  #pragma unroll
  for (int i=0;i<4;i++) out[(size_t)(c0+ty*4+i)*R + r0+tx] = f2b(tile[tx][ty*4+i]);
}

// ---------------- 256xBN 8-phase bf16 GEMM: C = A[M][K] * BT[N][K]^T ----------------
// K-split LDS regions (64B rows -> naturally conflict-optimal, coalesced staging),
// one region staged per phase into opposite parity, counted vmcnt(4)/(3),
// raw asm s_barriers, setprio around MFMA, XCD swizzle.
template<int OB, int BN>   // OB=1: bf16 C out; BN in {256,128}
__global__ __launch_bounds__(512,2) void k_gemm8(const unsigned short* __restrict__ A,
    const unsigned short* __restrict__ BT, void* __restrict__ Cv,
    int M, int N, int K, int nbx){
  constexpr int BCH  = BN*4;            // 16B chunks per B region
  constexpr int BISS = BCH/512;         // gld_lds issues per B region (2 or 1)
  constexpr int AFR  = (BN==256)?8:4;   // acc fragment rows per wave
  __shared__ __align__(16) unsigned short lds[(4096 + 4*BCH)*8];
  const int NT = K >> 6;
  int cpx = gridDim.x >> 3;
  int bid = blockIdx.x;
  int swz = (bid & 7)*cpx + (bid >> 3);
  int bm = (swz / nbx)*256, bn = (swz % nbx)*BN;
  int tid = threadIdx.x;
  int wave = tid >> 6, lane = tid & 63;
  int r = lane & 15, g = lane >> 4;
  int arow0 = (BN==256) ? (wave>>2)*128 : (wave>>1)*64;
  int bcol0 = (BN==256) ? (wave&3)*64  : (wave&1)*64;

  f32x4 acc[AFR][4];
  #pragma unroll
  for (int i=0;i<AFR;i++)
    #pragma unroll
    for (int j=0;j<4;j++){ acc[i][j][0]=0.f; acc[i][j][1]=0.f; acc[i][j][2]=0.f; acc[i][j][3]=0.f; }

  #define ACHO(p,kk) ((p)*2048 + (kk)*1024)
  #define BCHO(p,kk) (4096 + ((p)*2+(kk))*BCH)
  #define LDSA(p,kk,row) (*(const short8*)((const char*)lds + (size_t)((ACHO(p,kk) + (row)*4 + g)<<4)))
  #define LDSB(p,kk,row) (*(const short8*)((const char*)lds + (size_t)((BCHO(p,kk) + (row)*4 + g)<<4)))
  #define STG_A(p,kk,t) do{ int ts_ = ((t) < NT) ? (t) : (NT-1);                        \
    _Pragma("unroll") for (int i_=0;i_<2;++i_){ int c_ = tid + i_*512;                  \
      int row_ = c_>>2, g_ = c_&3;                                                      \
      gld_lds16(&A[(size_t)(bm+row_)*K + (size_t)ts_*64 + (kk)*32 + g_*8],              \
                (char*)lds + ((size_t)(ACHO(p,kk) + c_)<<4)); } }while(0)
  #define STG_B(p,kk,t) do{ int ts_ = ((t) < NT) ? (t) : (NT-1);                        \
    _Pragma("unroll") for (int i_=0;i_<BISS;++i_){ int c_ = tid + i_*512;               \
      int row_ = c_>>2, g_ = c_&3;                                                      \
      gld_lds16(&BT[(size_t)(bn+row_)*K + (size_t)ts_*64 + (kk)*32 + g_*8],             \
                (char*)lds + ((size_t)(BCHO(p,kk) + c_)<<4)); } }while(0)

  #define MMA4(off) _Pragma("unroll") for (int fr_=0;fr_<4;++fr_)                       \
      _Pragma("unroll") for (int fc_=0;fc_<4;++fc_)                                     \
        acc[(off)+fr_][fc_] = MFMA16(af[fr_], bf[fc_], acc[(off)+fr_][fc_]);

  #define BAR() asm volatile("s_barrier" ::: "memory")
  #define WAITL() do{ asm volatile("s_waitcnt lgkmcnt(0)" ::: "memory");                \
                      __builtin_amdgcn_sched_barrier(0); }while(0)
  #define VM(n) asm volatile("s_waitcnt vmcnt(" #n ")" ::: "memory")
  #define PRIO1 __builtin_amdgcn_s_setprio(1)
  #define PRIO0 __builtin_amdgcn_s_setprio(0)

  // ---- big tile: 4 phases/K-tile, stage order AK0,BK0,AK1,BK1 (t+1, opposite parity)
  #define KTILE256(p, t) do{                                                            \
    short8 af[4], bf[4];                                                                \
    _Pragma("unroll") for (int f_=0; f_<4; ++f_){                                       \
      af[f_] = LDSA(p,0, arow0 + f_*16 + r);                                            \
      bf[f_] = LDSB(p,0, bcol0 + f_*16 + r); }                                          \
    STG_A((p)^1, 0, (t)+1);                                                             \
    BAR(); WAITL();                                                                     \
    PRIO1; MMA4(0); PRIO0; BAR();                                                       \
    _Pragma("unroll") for (int f_=0; f_<4; ++f_)                                        \
      af[f_] = LDSA(p,0, arow0 + 64 + f_*16 + r);                                       \
    STG_B((p)^1, 0, (t)+1);                                                             \
    VM(4); BAR(); WAITL();                                                              \
    PRIO1; MMA4(4); PRIO0; BAR();                                                       \
    _Pragma("unroll") for (int f_=0; f_<4; ++f_){                                       \
      af[f_] = LDSA(p,1, arow0 + f_*16 + r);                                            \
      bf[f_] = LDSB(p,1, bcol0 + f_*16 + r); }                                          \
    STG_A((p)^1, 1, (t)+1);                                                             \
    BAR(); WAITL();                                                                     \
    PRIO1; MMA4(0); PRIO0; BAR();                                                       \
    _Pragma("unroll") for (int f_=0; f_<4; ++f_)                                        \
      af[f_] = LDSA(p,1, arow0 + 64 + f_*16 + r);                                       \
    STG_B((p)^1, 1, (t)+1);                                                             \
    VM(4); BAR(); WAITL();                                                              \
    PRIO1; MMA4(4); PRIO0; BAR();                                                       \
  }while(0)

  // ---- small tile: 2 phases/K-tile
  #define KTILE128(p, t) do{                                                            \
    short8 af[4], bf[4];                                                                \
    _Pragma("unroll") for (int f_=0; f_<4; ++f_){                                       \
      af[f_] = LDSA(p,0, arow0 + f_*16 + r);                                            \
      bf[f_] = LDSB(p,0, bcol0 + f_*16 + r); }                                          \
    STG_A((p)^1, 0, (t)+1); STG_B((p)^1, 0, (t)+1);                                     \
    VM(3); BAR(); WAITL();                                                              \
    PRIO1; MMA4(0); PRIO0; BAR();                                                       \
    _Pragma("unroll") for (int f_=0; f_<4; ++f_){                                       \
      af[f_] = LDSA(p,1, arow0 + f_*16 + r);                                            \
      bf[f_] = LDSB(p,1, bcol0 + f_*16 + r); }                                          \
    STG_A((p)^1, 1, (t)+1); STG_B((p)^1, 1, (t)+1);                                     \
    VM(3); BAR(); WAITL();                                                              \
    PRIO1; MMA4(0); PRIO0; BAR();                                                       \
  }while(0)

  // prologue: stage tile 0 (order AK0,BK0,AK1,BK1); drain K0 regions, leave K1 in flight
  STG_A(0,0,0); STG_B(0,0,0); STG_A(0,1,0); STG_B(0,1,0);
  if constexpr (BN==256) { VM(4); } else { VM(3); }
  BAR();

  if constexpr (BN==256){
    for (int tt=0; tt<NT; tt+=2){ KTILE256(0, tt); KTILE256(1, tt+1); }
  } else {
    for (int tt=0; tt<NT; tt+=2){ KTILE128(0, tt); KTILE128(1, tt+1); }
  }

  #pragma unroll
  for (int i=0;i<AFR;i++)
    #pragma unroll
    for (int j=0;j<4;j++)
      #pragma unroll
      for (int rr=0;rr<4;rr++){
        size_t idx = (size_t)(bm + arow0 + i*16 + 4*g + rr)*N + bn + bcol0 + j*16 + r;
        if (OB) ((unsigned short*)Cv)[idx] = f2b(acc[i][j][rr]);
        else    ((float*)Cv)[idx] = acc[i][j][rr];
      }

  #undef ACHO
  #undef BCHO
  #undef LDSA
  #undef LDSB
  #undef STG_A
  #undef STG_B
  #undef MMA4
  #undef BAR
  #undef WAITL
  #undef VM
  #undef PRIO1
  #undef PRIO0
  #undef KTILE256
  #undef KTILE128
}

// ---------------- RoPE + head split (bf16 qkv in); Q scaled by log2(e)/sqrt(128) ----------------
__global__ __launch_bounds__(256) void k_rope_split(const unsigned short* __restrict__ qkv,
    const float* __restrict__ fc, unsigned short* __restrict__ qb,
    unsigned short* __restrict__ kb, unsigned short* __restrict__ vb){
  int row = blockIdx.x;              // b*2048 + t
  int t = row & 2047, b = row >> 11;
  int tid = threadIdx.x;
  const unsigned short* qr = qkv + (size_t)row*3072;
  const float QS = 0.12751743f;      // log2(e)/sqrt(128)
  #pragma unroll
  for (int ii=0; ii<4; ii++){        // 1024 q pairs
    int p = tid + 256*ii;
    int h = p>>6, f = p&63;
    unsigned int pr = *(const unsigned int*)&qr[h*128 + 2*f];
    float x0 = b2f((unsigned short)(pr & 0xffff)), x1 = b2f((unsigned short)(pr >> 16));
    float2 cssn = *(const float2*)&fc[t*128 + 2*f];
    float o0 = (x0*cssn.x - x1*cssn.y)*QS, o1 = (x0*cssn.y + x1*cssn.x)*QS;
    size_t o = ((size_t)(b*16 + h)*2048 + t)*128 + 2*f;
    qb[o] = f2b(o0); qb[o+1] = f2b(o1);
  }
  {                                   // 256 k pairs
    int p = tid; int kh = p>>6, f = p&63;
    unsigned int pr = *(const unsigned int*)&qr[2048 + kh*128 + 2*f];
    float x0 = b2f((unsigned short)(pr & 0xffff)), x1 = b2f((unsigned short)(pr >> 16));
    float2 cssn = *(const float2*)&fc[t*128 + 2*f];
    float o0 = x0*cssn.x - x1*cssn.y, o1 = x0*cssn.y + x1*cssn.x;
    size_t o = ((size_t)(b*4 + kh)*2048 + t)*128 + 2*f;
    kb[o] = f2b(o0); kb[o+1] = f2b(o1);
  }
  #pragma unroll
  for (int ii=0; ii<2; ii++){         // 512 v elems
    int e = tid + 256*ii;
    int kh = e>>7, d = e&127;
    size_t o = ((size_t)(b*4 + kh)*2048 + t)*128 + d;
    vb[o] = qr[2560 + e];
  }
}

// ---------------- V transpose: [bk][2048][128] -> [bk][128][2048] ----------------
__global__ void k_transpose_v(const unsigned short* __restrict__ v,
                              unsigned short* __restrict__ vt){
  __shared__ unsigned short tile[32][33];
  int bk = blockIdx.z;
  int d0 = blockIdx.x*32, t0 = blockIdx.y*32;
  int tx = threadIdx.x, ty = threadIdx.y;
  const unsigned short* vp = v + (size_t)bk*2048*128;
  unsigned short* vtp = vt + (size_t)bk*128*2048;
  #pragma unroll
  for (int i=0;i<4;i++) tile[ty*4+i][tx] = vp[(t0+ty*4+i)*128 + d0+tx];
  __syncthreads();
  #pragma unroll
  for (int i=0;i<4;i++) vtp[(d0+ty*4+i)*2048 + t0+tx] = tile[tx][ty*4+i];
}

// ---------------- sliding-window flash attention, LDS-staged K/V ----------------
__global__ __launch_bounds__(256,2) void k_attn(const unsigned short* __restrict__ q,
    const unsigned short* __restrict__ k, const unsigned short* __restrict__ vt,
    unsigned short* __restrict__ y){
  int qb0 = blockIdx.x*64;
  int h = blockIdx.y, b = blockIdx.z;
  int kvh = h>>2;
  int tid = threadIdx.x, wave = tid>>6, lane = tid&63;
  int w0 = qb0 + wave*16;
  int r = lane&15, g = lane>>4;
  const unsigned short* qh = q + ((size_t)(b*16+h)*2048)*128;
  const unsigned short* kh = k + ((size_t)(b*4+kvh)*2048)*128;
  const unsigned short* vh = vt + ((size_t)(b*4+kvh)*128)*2048;

  __shared__ unsigned short Ks[2][64*128];   // [key][d], swizzled
  __shared__ unsigned short Vs[2][128*64];   // [d][key], swizzled
  __shared__ unsigned short plds[4][16][72];

  short8 qf[4];
  #pragma unroll
  for (int c=0;c<4;c++) qf[c] = *(const short8*)&qh[(w0+r)*128 + c*32 + g*8];

  f32x4 acc[8];
  #pragma unroll
  for (int d=0; d<8; d++){ acc[d][0]=0.f; acc[d][1]=0.f; acc[d][2]=0.f; acc[d][3]=0.f; }
  float m[4]  = {-1e30f,-1e30f,-1e30f,-1e30f};
  float ls[4] = {0.f,0.f,0.f,0.f};

  int lo = qb0 - 511; if (lo < 0) lo = 0;
  int t0 = lo & ~63;
  int nt = ((qb0 + 63) - t0)/64 + 1;
  int sw = (r&7)<<4;                 // per-lane read swizzle (row&7 == r&7)

  #define STAGE(bb, kt)                                                          \
    { _Pragma("unroll")                                                          \
      for (int p=0;p<4;p++){                                                     \
        int c = p*256 + tid;                                                     \
        int row = c>>4, col = (c&15)*16;                                         \
        gld_lds16((const char*)kh + (size_t)((kt)+row)*256 + (col ^ ((row&7)<<4)),\
                  (char*)&Ks[bb][0] + c*16);                                     \
      }                                                                          \
      _Pragma("unroll")                                                          \
      for (int p=0;p<4;p++){                                                     \
        int c = p*256 + tid;                                                     \
        int row = c>>3, col = (c&7)*16;                                          \
        gld_lds16((const char*)vh + (size_t)row*4096 + (size_t)(kt)*2 + (col ^ ((row&7)<<4)),\
                  (char*)&Vs[bb][0] + c*16);                                     \
      }                                                                          \
    }

  STAGE(0, t0);
  __syncthreads();
  int cur = 0;

  for (int it=0; it<nt; it++){
    int kt = t0 + it*64;
    if (it+1 < nt) STAGE(cur^1, t0 + (it+1)*64);

    bool use = (kt <= w0+15) && (kt+63 >= w0-511);
    if (use){
      f32x4 S[4];
      #pragma unroll
      for (int s=0;s<4;s++){
        f32x4 a; a[0]=0.f; a[1]=0.f; a[2]=0.f; a[3]=0.f;
        const char* kr = (const char*)&Ks[cur][0] + (s*16+r)*256;
        #pragma unroll
        for (int c=0;c<4;c++){
          short8 kf = *(const short8*)(kr + ((c*64 + g*16) ^ sw));
          a = MFMA16(qf[c], kf, a);
        }
        S[s] = a;
      }
      #pragma unroll
      for (int rr=0;rr<4;rr++){
        int i = w0 + 4*g + rr;
        float mx = -3e38f;
        #pragma unroll
        for (int s=0;s<4;s++){
          int j = kt + s*16 + r;
          bool valid = (j <= i) && (i - j < 512);
          float sv = valid ? S[s][rr] : -3e38f;
          S[s][rr] = sv;
          mx = fmaxf(mx, sv);
        }
        mx = fmaxf(mx, __shfl_xor(mx, 1));
        mx = fmaxf(mx, __shfl_xor(mx, 2));
        mx = fmaxf(mx, __shfl_xor(mx, 4));
        mx = fmaxf(mx, __shfl_xor(mx, 8));
        float mn = fmaxf(m[rr], mx);
        float al = exp2f(m[rr] - mn);
        m[rr] = mn;
        float ps = 0.f;
        #pragma unroll
        for (int s=0;s<4;s++){
          float p = exp2f(S[s][rr] - mn);
          S[s][rr] = p;
          ps += p;
        }
        ls[rr] = ls[rr]*al + ps;
        #pragma unroll
        for (int d=0;d<8;d++) acc[d][rr] *= al;
      }
      #pragma unroll
      for (int rr=0;rr<4;rr++)
        #pragma unroll
        for (int s=0;s<4;s++)
          plds[wave][4*g+rr][s*16+r] = f2b(S[s][rr]);
      short8 pf0 = *(const short8*)&plds[wave][r][g*8];
      short8 pf1 = *(const short8*)&plds[wave][r][32 + g*8];
      #pragma unroll
      for (int d=0;d<8;d++){
        const char* vr = (const char*)&Vs[cur][0] + (d*16+r)*128;
        short8 vf0 = *(const short8*)(vr + ((g*16) ^ sw));
        short8 vf1 = *(const short8*)(vr + ((64 + g*16) ^ sw));
        acc[d] = MFMA16(pf0, vf0, acc[d]);
        acc[d] = MFMA16(pf1, vf1, acc[d]);
      }
    }
    __syncthreads();
    cur ^= 1;
  }

  #pragma unroll
  for (int rr=0;rr<4;rr++){
    float s = ls[rr];
    s += __shfl_xor(s, 1);
    s += __shfl_xor(s, 2);
    s += __shfl_xor(s, 4);
    s += __shfl_xor(s, 8);
    float inv = 1.f/s;
    int i = w0 + 4*g + rr;
    #pragma unroll
    for (int d=0;d<8;d++)
      y[((size_t)(b*2048)+i)*2048 + h*128 + d*16 + r] = f2b(acc[d][rr]*inv);
  }
}

extern "C" void kernel_launch(void* const* d_in, const int* in_sizes, int n_in,
                              void* d_out, int out_size, void* d_ws, size_t ws_size,
                              hipStream_t stream) {
  const float* x      = (const float*)d_in[0];
  const float* w_attn = (const float*)d_in[1];
  const float* w_proj = (const float*)d_in[2];
  const float* fc     = (const float*)d_in[3];
  float* out = (float*)d_out;
  char* ws = (char*)d_ws;
  unsigned short* xb   = (unsigned short*)(ws);             // 16,777,216  x bf16
  unsigned short* wt   = (unsigned short*)(ws + 16777216);  // 12,582,912  w^T bf16 (reused)
  unsigned short* qkvb = (unsigned short*)(ws + 29360128);  // 25,165,824  qkv bf16
  unsigned short* yb   = (unsigned short*)(ws + 29360128);  // reuse after rope
  unsigned short* qb   = (unsigned short*)(ws + 54525952);  // 16,777,216
  unsigned short* kb   = (unsigned short*)(ws + 71303168);  //  4,194,304
  unsigned short* vb   = (unsigned short*)(ws + 75497472);  //  4,194,304
  unsigned short* vtb  = (unsigned short*)(ws + 79691776);  //  4,194,304

  k_convert_x<<<4096, 256, 0, stream>>>(x, xb, 8388608);
  k_transpose_convert<<<dim3(96,64), dim3(32,8), 0, stream>>>(w_attn, wt, 2048, 3072);
  k_gemm8<1,256><<<dim3(192), 512, 0, stream>>>(xb, wt, qkvb, 4096, 3072, 2048, 12);
  k_rope_split<<<4096, 256, 0, stream>>>(qkvb, fc, qb, kb, vb);
  k_transpose_v<<<dim3(4,64,8), dim3(32,8), 0, stream>>>(vb, vtb);
  k_transpose_convert<<<dim3(64,64), dim3(32,8), 0, stream>>>(w_proj, wt, 2048, 2048);
  k_attn<<<dim3(32,16,2), 256, 0, stream>>>(qb, kb, vtb, yb);
  k_gemm8<0,128><<<dim3(256), 512, 0, stream>>>(yb, wt, out, 4096, 2048, 2048, 16);
}